// Round 1
// baseline (146.647 us; speedup 1.0000x reference)
//
#include <hip/hip_runtime.h>
#include <hip/hip_bf16.h>
#include <stdint.h>

#define NB 8192
#define DK 256
#define GAMMA 10.0f
#define BM 256
#define BK 64
#define NKT (DK / BK)   // 4 K-chunks

typedef short short8 __attribute__((ext_vector_type(8)));
typedef float f32x4 __attribute__((ext_vector_type(4)));

__device__ __forceinline__ unsigned short f32_to_bf16(float f) {
  uint32_t u = __builtin_bit_cast(uint32_t, f);
  u += 0x7FFFu + ((u >> 16) & 1u);   // RNE; inputs are small finite values
  return (unsigned short)(u >> 16);
}

// One wave per row: compute 1/max(||row||,eps), scale (gamma folded into e), store bf16.
__global__ __launch_bounds__(256) void norm_kernel(const float* __restrict__ e,
                                                   const float* __restrict__ v,
                                                   unsigned short* __restrict__ ebf,
                                                   unsigned short* __restrict__ vbf) {
  int wave = threadIdx.x >> 6;
  int lane = threadIdx.x & 63;
  int row = blockIdx.x * 4 + wave;          // 0..16383
  const float* src;
  unsigned short* dst;
  float mul;
  if (row < NB) {
    src = e + (size_t)row * DK; dst = ebf + (size_t)row * DK; mul = GAMMA;
  } else {
    src = v + (size_t)(row - NB) * DK; dst = vbf + (size_t)(row - NB) * DK; mul = 1.0f;
  }
  float4 x = reinterpret_cast<const float4*>(src)[lane];   // 64 lanes * 4 = 256
  float ss = x.x * x.x + x.y * x.y + x.z * x.z + x.w * x.w;
  #pragma unroll
  for (int off = 32; off >= 1; off >>= 1) ss += __shfl_xor(ss, off);
  float s = mul / fmaxf(sqrtf(ss), 1e-8f);
  ushort4 o;
  o.x = f32_to_bf16(x.x * s);
  o.y = f32_to_bf16(x.y * s);
  o.z = f32_to_bf16(x.z * s);
  o.w = f32_to_bf16(x.w * s);
  reinterpret_cast<ushort4*>(dst)[lane] = o;
}

// 256x256 tile GEMM-like; K=256 in 4 double-buffered BK=64 chunks.
// LDS tiles [256 rows][64 bf16] with XOR swizzle c ^= ((r>>2)&7)<<4 applied on
// BOTH the global source address (global_load_lds writes linearly) and the
// ds_read address — rule 21 both-sides-or-neither.
__global__ __launch_bounds__(512, 2) void score_kernel(const unsigned short* __restrict__ ebf,
                                                       const unsigned short* __restrict__ vbf,
                                                       float* __restrict__ out) {
  __shared__ unsigned short lds[2][2][BM * BK];   // [buf][A/B], 32 KiB each = 128 KiB

  const int tid = threadIdx.x;
  const int w = tid >> 6;          // 0..7
  const int lane = tid & 63;
  const int lo16 = lane & 15;
  const int q4 = lane >> 4;        // 0..3
  const int wr = w >> 2;           // 0..1  (M)
  const int wc = w & 3;            // 0..3  (N)

  // XCD-aware swizzle: 1024 blocks, 8 XCDs, 128 contiguous tiles per XCD.
  int id = blockIdx.x;
  int nid = (id & 7) * 128 + (id >> 3);
  int bi = nid >> 5;               // 0..31
  int bj = nid & 31;

  const char* eB = (const char*)(ebf + (size_t)bi * BM * DK);
  const char* vB = (const char*)(vbf + (size_t)bj * BM * DK);

  auto stage = [&](int buf, int kt) {
    #pragma unroll
    for (int c = 0; c < 4; ++c) {
      int p = ((w * 4 + c) * 64 + lane) * 16;           // linear byte offset in 32 KiB tile
      int r = p >> 7;                                   // row (128 B rows)
      int lc = (p & 127) ^ (((r >> 2) & 7) << 4);       // inverse-swizzled logical col
      size_t goff = (size_t)r * (DK * 2) + (size_t)kt * (BK * 2) + (size_t)lc;
      unsigned short* dA = &lds[buf][0][(w * 4 + c) * 512];   // wave-uniform dest base
      unsigned short* dB = &lds[buf][1][(w * 4 + c) * 512];
      __builtin_amdgcn_global_load_lds((const __attribute__((address_space(1))) uint32_t*)(eB + goff),
                                       (__attribute__((address_space(3))) uint32_t*)dA, 16, 0, 0);
      __builtin_amdgcn_global_load_lds((const __attribute__((address_space(1))) uint32_t*)(vB + goff),
                                       (__attribute__((address_space(3))) uint32_t*)dB, 16, 0, 0);
    }
  };

  f32x4 acc[8][4];
  #pragma unroll
  for (int m = 0; m < 8; ++m)
    #pragma unroll
    for (int n = 0; n < 4; ++n)
      #pragma unroll
      for (int q = 0; q < 4; ++q)
        acc[m][n][q] = 0.0f;

  stage(0, 0);
  __syncthreads();

  #pragma unroll
  for (int kt = 0; kt < NKT; ++kt) {
    int buf = kt & 1;
    if (kt + 1 < NKT) stage(buf ^ 1, kt + 1);
    const char* LA = (const char*)&lds[buf][0][0];
    const char* LB = (const char*)&lds[buf][1][0];
    #pragma unroll
    for (int ks = 0; ks < 2; ++ks) {              // two K=32 steps per BK=64
      short8 af[8];
      short8 bfr[4];
      #pragma unroll
      for (int m = 0; m < 8; ++m) {
        int r = wr * 128 + m * 16 + lo16;
        int q = r * 128 + ((ks * 64 + q4 * 16) ^ (((r >> 2) & 7) << 4));
        af[m] = *(const short8*)(LA + q);
      }
      #pragma unroll
      for (int n = 0; n < 4; ++n) {
        int r = wc * 64 + n * 16 + lo16;
        int q = r * 128 + ((ks * 64 + q4 * 16) ^ (((r >> 2) & 7) << 4));
        bfr[n] = *(const short8*)(LB + q);
      }
      #pragma unroll
      for (int m = 0; m < 8; ++m)
        #pragma unroll
        for (int n = 0; n < 4; ++n)
          acc[m][n] = __builtin_amdgcn_mfma_f32_16x16x32_bf16(af[m], bfr[n], acc[m][n], 0, 0, 0);
    }
    __syncthreads();
  }

  // Epilogue: E = exp(acc) (gamma already folded); row sums -> out[0..NB),
  // col sums -> out[NB..2NB). C/D layout: col = lane&15, row = (lane>>4)*4 + reg.
  float colpart[4] = {0.f, 0.f, 0.f, 0.f};
  #pragma unroll
  for (int m = 0; m < 8; ++m) {
    float rowpart[4] = {0.f, 0.f, 0.f, 0.f};
    #pragma unroll
    for (int n = 0; n < 4; ++n) {
      #pragma unroll
      for (int g = 0; g < 4; ++g) {
        float ev = __expf(acc[m][n][g]);
        rowpart[g] += ev;
        colpart[n] += ev;
      }
    }
    #pragma unroll
    for (int g = 0; g < 4; ++g) {
      float s = rowpart[g];
      s += __shfl_xor(s, 1);
      s += __shfl_xor(s, 2);
      s += __shfl_xor(s, 4);
      s += __shfl_xor(s, 8);
      if (lo16 == ((m * 4 + g) & 15)) {
        int row = bi * BM + wr * 128 + m * 16 + q4 * 4 + g;
        atomicAdd(&out[row], s);
      }
    }
  }
  #pragma unroll
  for (int n = 0; n < 4; ++n) {
    float s = colpart[n];
    s += __shfl_xor(s, 16);
    s += __shfl_xor(s, 32);
    if (q4 == 0) {
      int col = bj * BM + wc * 64 + n * 16 + lo16;
      atomicAdd(&out[NB + col], s);
    }
  }
}

extern "C" void kernel_launch(void* const* d_in, const int* in_sizes, int n_in,
                              void* d_out, int out_size, void* d_ws, size_t ws_size,
                              hipStream_t stream) {
  const float* e = (const float*)d_in[0];
  const float* v = (const float*)d_in[1];
  float* out = (float*)d_out;
  unsigned short* ebf = (unsigned short*)d_ws;                 // 8192*256 bf16 = 4 MiB
  unsigned short* vbf = ebf + (size_t)NB * DK;                 // + 4 MiB
  hipMemsetAsync(d_out, 0, (size_t)2 * NB * sizeof(float), stream);
  hipLaunchKernelGGL(norm_kernel, dim3((2 * NB) / 4), dim3(256), 0, stream, e, v, ebf, vbf);
  hipLaunchKernelGGL(score_kernel, dim3((NB / BM) * (NB / BM)), dim3(512), 0, stream, ebf, vbf, out);
}